// Round 13
// baseline (300.334 us; speedup 1.0000x reference)
//
#include <hip/hip_runtime.h>

typedef __bf16 bf16;
typedef bf16 bf16x4 __attribute__((ext_vector_type(4)));
typedef bf16 bf16x8 __attribute__((ext_vector_type(8)));
typedef float f32x4 __attribute__((ext_vector_type(4)));

#define D_MODEL 1024
#define NHEAD   16
#define D_K     64
#define BATCH   8
#define SEQL    1024
#define MROWS   (BATCH*SEQL)   // 8192

// ---------------- f32 -> bf16 conversion (7 arrays in one launch) ----------------
struct Cvt7 {
    const float* s[7];
    bf16*        d[7];
    int          n[7];
};

__global__ __launch_bounds__(256) void cvt7_kernel(Cvt7 a) {
    const int y = blockIdx.y;
    const float* __restrict__ src = a.s[y];
    bf16* __restrict__ dst = a.d[y];
    const int n4 = a.n[y] >> 2;
    const int stride = gridDim.x * blockDim.x;
    for (int i = blockIdx.x * blockDim.x + threadIdx.x; i < n4; i += stride) {
        float4 v = ((const float4*)src)[i];
        bf16x4 o = { (bf16)v.x, (bf16)v.y, (bf16)v.z, (bf16)v.w };
        ((bf16x4*)dst)[i] = o;
    }
}

// ---------------- GEMM core (R1-proven m97 structure): C = A * B^T ----------------
// 128x128 tile, BK=32, 4 waves (2x2 of 64x64), global_load_lds w=16.
// R2 lesson: 256x256 tile regressed at N=1024 (4 col-tiles -> 1.5 blk/CU imbalance).
#define BM 128
#define BN 128
#define BK 32

__device__ __forceinline__ void gemm_core(const bf16* __restrict__ A, const bf16* __restrict__ B,
                                          int bm, int bn, int K,
                                          bf16* lA, bf16* lB, f32x4 (&acc)[4][4]) {
    const int t = threadIdx.x;
    const int lane = t & 63, w = t >> 6;
    const int wr = w >> 1, wc = w & 1;
    const int r = lane & 15, kb = lane >> 4;

    for (int k0 = 0; k0 < K; k0 += BK) {
        __syncthreads();
        #pragma unroll
        for (int i = 0; i < 2; ++i) {
            const int off = i * 4096 + w * 1024 + lane * 16;
            const int row = off >> 6;
            const int cb  = off & 63;
            const bf16* srcA = A + (size_t)(bm + row) * K + k0 + (cb >> 1);
            const bf16* srcB = B + (size_t)(bn + row) * K + k0 + (cb >> 1);
            __builtin_amdgcn_global_load_lds(
                (const __attribute__((address_space(1))) unsigned int*)srcA,
                (__attribute__((address_space(3))) unsigned int*)((char*)lA + i * 4096 + w * 1024),
                16, 0, 0);
            __builtin_amdgcn_global_load_lds(
                (const __attribute__((address_space(1))) unsigned int*)srcB,
                (__attribute__((address_space(3))) unsigned int*)((char*)lB + i * 4096 + w * 1024),
                16, 0, 0);
        }
        __syncthreads();

        bf16x8 af[4], bfr[4];
        #pragma unroll
        for (int m = 0; m < 4; ++m)
            af[m] = *(const bf16x8*)(lA + (wr * 64 + m * 16 + r) * BK + kb * 8);
        #pragma unroll
        for (int n = 0; n < 4; ++n)
            bfr[n] = *(const bf16x8*)(lB + (wc * 64 + n * 16 + r) * BK + kb * 8);
        #pragma unroll
        for (int m = 0; m < 4; ++m)
            #pragma unroll
            for (int n = 0; n < 4; ++n)
                acc[m][n] = __builtin_amdgcn_mfma_f32_16x16x32_bf16(af[m], bfr[n], acc[m][n], 0, 0, 0);
    }
}

// ---------------- Q/K/V projections (one launch, z = 0/1/2) ----------------
__global__ __launch_bounds__(256) void proj3_kernel(
        const bf16* __restrict__ xq, const bf16* __restrict__ xk, const bf16* __restrict__ xv,
        const bf16* __restrict__ Wqb, const bf16* __restrict__ Wkb, const bf16* __restrict__ Wvb,
        const float* __restrict__ bq, const float* __restrict__ bk, const float* __restrict__ bv,
        bf16* __restrict__ Qp, bf16* __restrict__ Kp, bf16* __restrict__ Vt) {
    __shared__ bf16 lA[BM * BK], lB[BN * BK];
    const int z = blockIdx.z;
    const bf16* A    = (z == 0) ? xq  : (z == 1) ? xk  : xv;
    const bf16* Bm   = (z == 0) ? Wqb : (z == 1) ? Wkb : Wvb;
    const float* bias = (z == 0) ? bq : (z == 1) ? bk  : bv;
    const int bm = blockIdx.x * BM, bn = blockIdx.y * BN;

    f32x4 acc[4][4] = {};
    gemm_core(A, Bm, bm, bn, D_MODEL, lA, lB, acc);

    const int lane = threadIdx.x & 63, w = threadIdx.x >> 6;
    const int wr = w >> 1, wc = w & 1, r = lane & 15, g = lane >> 4;
    #pragma unroll
    for (int n = 0; n < 4; ++n) {
        const int col = bn + wc * 64 + n * 16 + r;
        const float bvl = bias[col];
        const int h = col >> 6, d = col & 63;
        #pragma unroll
        for (int m = 0; m < 4; ++m) {
            #pragma unroll
            for (int j = 0; j < 4; ++j) {
                const int row = bm + wr * 64 + m * 16 + g * 4 + j;
                const float v = acc[m][n][j] + bvl;
                const int b = row >> 10, s = row & (SEQL - 1);
                const int bh = b * NHEAD + h;
                if (z == 0) {
                    Qp[((size_t)bh * SEQL + s) * D_K + d] = (bf16)v;
                } else if (z == 1) {
                    Kp[((size_t)bh * SEQL + s) * D_K + d] = (bf16)v;
                } else {
                    Vt[((size_t)bh * D_K + d) * SEQL + s] = (bf16)v;
                }
            }
        }
    }
}

// ---------------- output projection: out = AO * Wo^T + bo (f32 out) ----------------
__global__ __launch_bounds__(256) void outproj_kernel(
        const bf16* __restrict__ AO, const bf16* __restrict__ Wob,
        const float* __restrict__ bo, float* __restrict__ out) {
    __shared__ bf16 lA[BM * BK], lB[BN * BK];
    const int bm = blockIdx.x * BM, bn = blockIdx.y * BN;
    f32x4 acc[4][4] = {};
    gemm_core(AO, Wob, bm, bn, D_MODEL, lA, lB, acc);

    const int lane = threadIdx.x & 63, w = threadIdx.x >> 6;
    const int wr = w >> 1, wc = w & 1, r = lane & 15, g = lane >> 4;
    #pragma unroll
    for (int n = 0; n < 4; ++n) {
        const int col = bn + wc * 64 + n * 16 + r;
        const float bvl = bo[col];
        #pragma unroll
        for (int m = 0; m < 4; ++m)
            #pragma unroll
            for (int j = 0; j < 4; ++j) {
                const int row = bm + wr * 64 + m * 16 + g * 4 + j;
                out[(size_t)row * D_MODEL + col] = acc[m][n][j] + bvl;
            }
    }
}

// ---------------- fused masked flash attention: QBLK=128, K/V amortized 2x ----------------
// R6/R8 (proven): block-level LDS staging, line-granular global access, 2-barrier loop.
// R7/R9/R10: all explicit pipelining regressed. R11/R12: occupancy levers neutral.
// Accounting: staged volume was 1 GB (K8+V8+M16 KB x 16 tiles x 2048 blocks) through a
// VMEM pipe measured saturated at ~11 B/cy/CU. R13 single variable: QBLK 64->128 — each
// wave owns 32 q rows (2 q-groups of 16), K/V tiles serve 2x the output: staged volume
// -> 768 MB, and K/V fragments are reused across both q-groups (2x MFMA per LDS read).
// LDS K8+V8+M32 = 48KB -> 3 blocks/CU (occupancy non-binding per R11/R12). P folds into
// the wave's 8KB mbuf quarter (P < 4KB; q-group 1's mask rows >= 4KB; mv read before
// P-writes within q-group 0 -> no alias). Swapped QK^T; no max-subtraction; deferred sum.
__global__ __launch_bounds__(256, 3) void attn_kernel(
        const bf16* __restrict__ Qp, const bf16* __restrict__ Kp, const bf16* __restrict__ Vt,
        const unsigned int* __restrict__ mask, bf16* __restrict__ AO) {
    __shared__ char kbuf[8192];            // K tile [64 s][128B], chunk-swizzled
    __shared__ char vbuf[8192];            // V^T tile [64 d][128B], chunk-swizzled
    __shared__ char mbuf[32768];           // mask tile [128 q][256B]; wave quarter doubles as P
    // bijective remap over 1024 blocks (8 xcd x 16 bh x 8 qt)
    const int lin = blockIdx.x + blockIdx.y * gridDim.x;
    const int xcd = lin & 7, pos = lin >> 3;
    const int bh  = xcd * 16 + (pos >> 3);
    const int qt  = pos & 7;
    const int b = bh >> 4, h = bh & 15;
    const int t = threadIdx.x, lane = t & 63, w = t >> 6;
    const int q0 = qt * 128;               // block q-tile; wave w owns rows w*32 .. w*32+31
    const int r = lane & 15, g = lane >> 4;

    const char* __restrict__ Kb = (const char*)(Kp + (size_t)bh * SEQL * D_K);
    const char* __restrict__ Vb = (const char*)(Vt + (size_t)bh * D_K * SEQL);
    const char* __restrict__ Mb = (const char*)(mask + ((size_t)bh * SEQL + q0) * SEQL);

    // Q fragments for both q-groups: lane holds Q[q = w*32 + qq*16 + r][kk*32+g*8..+8]
    const bf16* __restrict__ Qh = Qp + ((size_t)bh * SEQL + q0 + w * 32) * D_K;
    bf16x8 qf[2][2];
    #pragma unroll
    for (int qq = 0; qq < 2; ++qq)
        #pragma unroll
        for (int kk = 0; kk < 2; ++kk)
            qf[qq][kk] = *(const bf16x8*)(Qh + (qq * 16 + r) * D_K + kk * 32 + g * 8);

    f32x4 o[2][4] = {};           // O^T per q-group: o[qq][n][j] = O[q][d = n*16 + g*4 + j]
    float psum[2] = {0.f, 0.f};
    char* P = mbuf + w * 8192;    // wave-private quarter; P uses first 4KB
    const int swz = (r & 7) << 4;

    for (int s0 = 0; s0 < SEQL; s0 += 64) {
        __syncthreads();   // prev tile's ds_reads done before overwrite
        // ---- stage K (2), V (2), M (8) gload_lds; linear dest, swizzled source ----
        #pragma unroll
        for (int i = 0; i < 2; ++i) {
            const int slot = i * 256 + t;
            const int row = slot >> 3, ch = slot & 7;
            const char* srcK = Kb + (size_t)(s0 + row) * 128 + ((ch * 16) ^ ((row & 7) << 4));
            const char* srcV = Vb + (size_t)row * (SEQL * 2) + s0 * 2 + ((ch * 16) ^ ((row & 7) << 4));
            __builtin_amdgcn_global_load_lds(
                (const __attribute__((address_space(1))) unsigned int*)srcK,
                (__attribute__((address_space(3))) unsigned int*)(kbuf + i * 4096 + w * 1024),
                16, 0, 0);
            __builtin_amdgcn_global_load_lds(
                (const __attribute__((address_space(1))) unsigned int*)srcV,
                (__attribute__((address_space(3))) unsigned int*)(vbuf + i * 4096 + w * 1024),
                16, 0, 0);
        }
        #pragma unroll
        for (int i = 0; i < 8; ++i) {
            const int slot = i * 256 + t;
            const int row = slot >> 4, ch = slot & 15;
            const char* srcM = Mb + (size_t)row * (SEQL * 4) + s0 * 4 + ((ch * 16) ^ ((row & 7) << 4));
            __builtin_amdgcn_global_load_lds(
                (const __attribute__((address_space(1))) unsigned int*)srcM,
                (__attribute__((address_space(3))) unsigned int*)(mbuf + i * 4096 + w * 1024),
                16, 0, 0);
        }
        __syncthreads();   // staging visible (compiler drains vmcnt before barrier)

        // ---- QK^T for both q-groups, K fragments loaded ONCE ----
        bf16x8 kf[4][2];
        #pragma unroll
        for (int n = 0; n < 4; ++n)
            #pragma unroll
            for (int kk = 0; kk < 2; ++kk)
                kf[n][kk] = *(const bf16x8*)(kbuf + (n * 16 + r) * 128 + ((kk * 64 + g * 16) ^ swz));
        f32x4 sf[2][4] = {};
        __builtin_amdgcn_s_setprio(1);
        #pragma unroll
        for (int qq = 0; qq < 2; ++qq)
            #pragma unroll
            for (int n = 0; n < 4; ++n)
                #pragma unroll
                for (int kk = 0; kk < 2; ++kk)
                    sf[qq][n] = __builtin_amdgcn_mfma_f32_16x16x32_bf16(kf[n][kk], qf[qq][kk], sf[qq][n], 0, 0, 0);
        __builtin_amdgcn_s_setprio(0);
        // ---- mask + exp + P-write per q-group (mv read BEFORE P writes; qq=1 mask rows
        //      live at quarter offsets >=4KB, P stays <4KB -> no alias) ----
        #pragma unroll
        for (int qq = 0; qq < 2; ++qq) {
            const int mrow = w * 32 + qq * 16 + r;
            uint4 mv[4];
            #pragma unroll
            for (int n = 0; n < 4; ++n)
                mv[n] = *(const uint4*)(mbuf + mrow * 256 + ((n * 64 + g * 16) ^ swz));
            #pragma unroll
            for (int n = 0; n < 4; ++n) {
                const float p0 = mv[n].x ? __expf(sf[qq][n][0] * 0.125f) : 0.f;
                const float p1 = mv[n].y ? __expf(sf[qq][n][1] * 0.125f) : 0.f;
                const float p2 = mv[n].z ? __expf(sf[qq][n][2] * 0.125f) : 0.f;
                const float p3 = mv[n].w ? __expf(sf[qq][n][3] * 0.125f) : 0.f;
                psum[qq] += (p0 + p1) + (p2 + p3);
                bf16x4 pb = { (bf16)p0, (bf16)p1, (bf16)p2, (bf16)p3 };
                *(bf16x4*)(P + (((qq * 16 + r) * 128 + n * 32 + g * 8) ^ swz)) = pb;
            }
        }
        // ---- PV for both q-groups, V fragments loaded ONCE ----
        bf16x8 pf[2][2];
        #pragma unroll
        for (int qq = 0; qq < 2; ++qq)
            #pragma unroll
            for (int kk = 0; kk < 2; ++kk)
                pf[qq][kk] = *(const bf16x8*)(P + (((qq * 16 + r) * 128 + kk * 64 + g * 16) ^ swz));
        __builtin_amdgcn_s_setprio(1);
        #pragma unroll
        for (int n = 0; n < 4; ++n) {
            const int vrow = n * 16 + r;
            bf16x8 vf0 = *(const bf16x8*)(vbuf + vrow * 128 + ((0 * 64 + g * 16) ^ swz));
            bf16x8 vf1 = *(const bf16x8*)(vbuf + vrow * 128 + ((1 * 64 + g * 16) ^ swz));
            #pragma unroll
            for (int qq = 0; qq < 2; ++qq) {
                o[qq][n] = __builtin_amdgcn_mfma_f32_16x16x32_bf16(vf0, pf[qq][0], o[qq][n], 0, 0, 0);
                o[qq][n] = __builtin_amdgcn_mfma_f32_16x16x32_bf16(vf1, pf[qq][1], o[qq][n], 0, 0, 0);
            }
        }
        __builtin_amdgcn_s_setprio(0);
    }

    // deferred row-sums + epilogue per q-group
    #pragma unroll
    for (int qq = 0; qq < 2; ++qq) {
        float ps = psum[qq];
        ps += __shfl_xor(ps, 16);
        ps += __shfl_xor(ps, 32);
        const float inv = 1.0f / ps;
        const size_t rowbase = ((size_t)(b * SEQL + q0 + w * 32 + qq * 16 + r)) * D_MODEL + h * D_K;
        #pragma unroll
        for (int n = 0; n < 4; ++n) {
            bf16x4 ob = { (bf16)(o[qq][n][0] * inv), (bf16)(o[qq][n][1] * inv),
                          (bf16)(o[qq][n][2] * inv), (bf16)(o[qq][n][3] * inv) };
            *(bf16x4*)(AO + rowbase + n * 16 + g * 4) = ob;
        }
    }
}

// ---------------- launch ----------------
extern "C" void kernel_launch(void* const* d_in, const int* in_sizes, int n_in,
                              void* d_out, int out_size, void* d_ws, size_t ws_size,
                              hipStream_t stream) {
    const float* q    = (const float*)d_in[0];
    const float* k    = (const float*)d_in[1];
    const float* v    = (const float*)d_in[2];
    const unsigned int* mask = (const unsigned int*)d_in[3];
    const float* Wq = (const float*)d_in[4];
    const float* bq = (const float*)d_in[5];
    const float* Wk = (const float*)d_in[6];
    const float* bk = (const float*)d_in[7];
    const float* Wv = (const float*)d_in[8];
    const float* bv = (const float*)d_in[9];
    const float* Wo = (const float*)d_in[10];
    const float* bo = (const float*)d_in[11];

    char* ws = (char*)d_ws;
    const size_t MB = 1u << 20;
    bf16* qb  = (bf16*)(ws + 0 * MB);
    bf16* kb  = (bf16*)(ws + 16 * MB);
    bf16* vb  = (bf16*)(ws + 32 * MB);
    bf16* Wqb = (bf16*)(ws + 48 * MB);
    bf16* Wkb = (bf16*)(ws + 50 * MB);
    bf16* Wvb = (bf16*)(ws + 52 * MB);
    bf16* Wob = (bf16*)(ws + 54 * MB);
    bf16* Qp  = (bf16*)(ws + 56 * MB);
    bf16* Kp  = (bf16*)(ws + 72 * MB);
    bf16* Vt  = (bf16*)(ws + 88 * MB);
    bf16* AO  = (bf16*)(ws + 104 * MB);   // 120 MiB total

    Cvt7 c;
    c.s[0] = q;  c.d[0] = qb;  c.n[0] = MROWS * D_MODEL;
    c.s[1] = k;  c.d[1] = kb;  c.n[1] = MROWS * D_MODEL;
    c.s[2] = v;  c.d[2] = vb;  c.n[2] = MROWS * D_MODEL;
    c.s[3] = Wq; c.d[3] = Wqb; c.n[3] = D_MODEL * D_MODEL;
    c.s[4] = Wk; c.d[4] = Wkb; c.n[4] = D_MODEL * D_MODEL;
    c.s[5] = Wv; c.d[5] = Wvb; c.n[5] = D_MODEL * D_MODEL;
    c.s[6] = Wo; c.d[6] = Wob; c.n[6] = D_MODEL * D_MODEL;
    cvt7_kernel<<<dim3(1024, 7), 256, 0, stream>>>(c);

    proj3_kernel<<<dim3(MROWS / BM, D_MODEL / BN, 3), 256, 0, stream>>>(
        qb, kb, vb, Wqb, Wkb, Wvb, bq, bk, bv, Qp, Kp, Vt);

    attn_kernel<<<dim3(SEQL / 128, BATCH * NHEAD), 256, 0, stream>>>(Qp, Kp, Vt, mask, AO);

    outproj_kernel<<<dim3(MROWS / BM, D_MODEL / BN), 256, 0, stream>>>(AO, Wob, bo, (float*)d_out);
}